// Round 17
// baseline (292.194 us; speedup 1.0000x reference)
//
#include <hip/hip_runtime.h>
#include <hip/hip_bf16.h>
#include <math.h>

typedef unsigned short u16;
typedef unsigned int u32;
typedef __attribute__((ext_vector_type(8))) short bf16x8;   // 8 bf16 = 4 VGPRs
typedef __attribute__((ext_vector_type(4))) float f32x4;

constexpr int Bc = 2, Sc = 2048, Dc = 2048, Hc = 16, HDc = 128;
constexpr int Mc = Bc * Sc;                     // 4096
constexpr float SCALE = 0.08838834764831845f;   // 1/sqrt(128)
constexpr float LOG2E = 1.4426950408889634f;

__device__ inline u16 f2bf(float f) {
  __hip_bfloat16 h = __float2bfloat16(f);
  return __builtin_bit_cast(u16, h);
}

typedef const __attribute__((address_space(1))) u32 glb_u32;
typedef __attribute__((address_space(3))) u32 lds_u32;
__device__ inline void gload16(const void* g, void* l) {
  // async global->LDS, 16B/lane; LDS dest is wave-uniform base + lane*16
  __builtin_amdgcn_global_load_lds((glb_u32*)g, (lds_u32*)l, 16, 0, 0);
}

// ---------------- fp32 -> bf16 convert (hidden + 4 weights) ----------------
__global__ __launch_bounds__(256) void cvt5(
    const float* __restrict__ s0, u16* __restrict__ d0, int n0,
    const float* __restrict__ s1, u16* __restrict__ d1, int n1,
    const float* __restrict__ s2, u16* __restrict__ d2, int n2,
    const float* __restrict__ s3, u16* __restrict__ d3, int n3,
    const float* __restrict__ s4, u16* __restrict__ d4, int n4) {
  int i = blockIdx.x * 256 + threadIdx.x;   // float4 index
  const float* s; u16* d;
  if (i < n0) { s = s0; d = d0; }
  else { i -= n0;
    if (i < n1) { s = s1; d = d1; }
    else { i -= n1;
      if (i < n2) { s = s2; d = d2; }
      else { i -= n2;
        if (i < n3) { s = s3; d = d3; }
        else { i -= n3;
          if (i >= n4) return;
          s = s4; d = d4; } } } }
  float4 v = reinterpret_cast<const float4*>(s)[i];
  ushort4 o;
  o.x = f2bf(v.x); o.y = f2bf(v.y); o.z = f2bf(v.z); o.w = f2bf(v.w);
  reinterpret_cast<ushort4*>(d)[i] = o;
}

// ======== Q+K fused GEMM, 256x256 tile, 8 waves, counted-vmcnt dbuf =======
__global__ __launch_bounds__(512, 2) void qk_gemm8(
    const u16* __restrict__ A, const u16* __restrict__ Wq,
    const u16* __restrict__ Wk, const float* __restrict__ bq,
    const float* __restrict__ bk, u16* __restrict__ qout,
    u16* __restrict__ kout) {
  __shared__ u16 lds[65536];      // 128 KB
  char* L = (char*)lds;
  const int t = threadIdx.x, w = t >> 6, lane = t & 63, g = lane >> 4, c = lane & 15;
  const int wm = w >> 2, wn = w & 3;           // 2M x 4N wave grid
  const int m0 = blockIdx.y * 256, n0 = blockIdx.x * 256;
  const int z = blockIdx.z;
  const u16* W = z ? Wk : Wq;
  const float* bias = z ? bk : bq;
  const float scale = z ? 1.0f : SCALE * LOG2E;

  f32x4 acc[8][4];
#pragma unroll
  for (int m = 0; m < 8; ++m)
#pragma unroll
    for (int n = 0; n < 4; ++n) acc[m][n] = 0.f;

  const u16* sPtr[8];
  int dOff[8];
#pragma unroll
  for (int i = 0; i < 8; ++i) {
    int i2 = i & 3;
    int u = i2 * 512 + t;
    int row = u >> 3, p = u & 7;
    int cu = (p ^ row) & 7;
    const u16* base = (i < 4) ? (A + (size_t)(m0 + row) * Dc)
                              : (W + (size_t)(n0 + row) * Dc);
    sPtr[i] = base + cu * 8;
    dOff[i] = ((i >= 4) ? 32768 : 0) + (i2 >> 1) * 16384 +
              ((i2 & 1) * 512 + (t & 448)) * 16;
  }

  auto STAGE = [&](int d) {
#pragma unroll
    for (int i = 0; i < 8; ++i) {
      gload16(sPtr[i], L + d * 65536 + dOff[i]);
      sPtr[i] += 64;
    }
  };

  STAGE(0);
  asm volatile("s_waitcnt vmcnt(0)" ::: "memory");
  asm volatile("s_barrier" ::: "memory");

  int cur = 0;
  const char* AbBase = L + wm * 16384;
  const char* BbBase = L + 32768 + (wn >> 1) * 16384;
  const int rB0 = (wn & 1) * 64;

#pragma unroll 1
  for (int s = 0; s < 32; ++s) {
    if (s + 1 < 32) {
      STAGE(cur ^ 1);
      asm volatile("s_waitcnt vmcnt(8)" ::: "memory");
    } else {
      asm volatile("s_waitcnt vmcnt(0)" ::: "memory");
    }
    asm volatile("s_barrier" ::: "memory");

    const char* Ab = AbBase + cur * 65536;
    const char* Bb = BbBase + cur * 65536;
#pragma unroll
    for (int mh = 0; mh < 2; ++mh)
#pragma unroll
      for (int ks = 0; ks < 2; ++ks) {
        bf16x8 af[4], bf[4];
#pragma unroll
        for (int m4 = 0; m4 < 4; ++m4) {
          int row = (mh * 4 + m4) * 16 + c;
          af[m4] = *(const bf16x8*)(Ab + row * 128 + (((ks * 4 + g) ^ row) & 7) * 16);
        }
#pragma unroll
        for (int n = 0; n < 4; ++n) {
          int row = rB0 + n * 16 + c;
          bf[n] = *(const bf16x8*)(Bb + row * 128 + (((ks * 4 + g) ^ row) & 7) * 16);
        }
        __builtin_amdgcn_s_setprio(1);
#pragma unroll
        for (int m4 = 0; m4 < 4; ++m4)
#pragma unroll
          for (int n = 0; n < 4; ++n)
            acc[mh * 4 + m4][n] =
                __builtin_amdgcn_mfma_f32_16x16x32_bf16(af[m4], bf[n], acc[mh * 4 + m4][n], 0, 0, 0);
        __builtin_amdgcn_s_setprio(0);
      }

    asm volatile("s_barrier" ::: "memory");
    cur ^= 1;
  }

  u16* outp = z ? kout : qout;
#pragma unroll
  for (int n = 0; n < 4; ++n) {
    int col = n0 + wn * 64 + n * 16 + c;
    float bvv = bias[col];
    int h = col >> 7, d = col & (HDc - 1);
#pragma unroll
    for (int m = 0; m < 8; ++m)
#pragma unroll
      for (int r = 0; r < 4; ++r) {
        int row = m0 + wm * 128 + m * 16 + g * 4 + r;
        int b = row >> 11, si = row & (Sc - 1);
        outp[((size_t)((b * Hc + h) * Sc + si)) * HDc + d] =
            f2bf((acc[m][n][r] + bvv) * scale);
      }
  }
}

// ------- V GEMM (128², counted-vmcnt dbuf; MODE2 transpose + k-perm) -------
constexpr int GBM = 128, GBN = 128, GBK = 64;

__global__ __launch_bounds__(256) void v_gemm(
    const u16* __restrict__ A, const u16* __restrict__ W,
    const float* __restrict__ bias, u16* __restrict__ vout) {
  __shared__ u16 smem[32768];     // 64KB: 2 × (16KB A + 16KB B); CT reuses
  char* L = (char*)smem;
  const int t = threadIdx.x;
  const int w = t >> 6, lane = t & 63, g = lane >> 4, c = lane & 15;
  const int wm = w >> 1, wn = w & 1;
  const int m0 = blockIdx.y * GBM, n0 = blockIdx.x * GBN;

  f32x4 acc[4][4];
#pragma unroll
  for (int m = 0; m < 4; ++m)
#pragma unroll
    for (int n = 0; n < 4; ++n) acc[m][n] = 0.f;

  const u16* sA[4];
  const u16* sB[4];
  int dA[4];
#pragma unroll
  for (int i = 0; i < 4; ++i) {
    int u = i * 256 + t;
    int row = u >> 3, p = u & 7;
    int cu = (p ^ row) & 7;
    sA[i] = A + (size_t)(m0 + row) * Dc + cu * 8;
    sB[i] = W + (size_t)(n0 + row) * Dc + cu * 8;
    dA[i] = (i * 256 + (t & 192)) * 16;
  }
  auto STG = [&](int d) {
#pragma unroll
    for (int i = 0; i < 4; ++i) {
      gload16(sA[i], L + d * 32768 + dA[i]);
      sA[i] += 64;
    }
#pragma unroll
    for (int i = 0; i < 4; ++i) {
      gload16(sB[i], L + d * 32768 + 16384 + dA[i]);
      sB[i] += 64;
    }
  };

  STG(0);
  int cur = 0;
#pragma unroll 1
  for (int s = 0; s < 32; ++s) {
    if (s + 1 < 32) {
      STG(cur ^ 1);
      asm volatile("s_waitcnt vmcnt(8)" ::: "memory");
    } else {
      asm volatile("s_waitcnt vmcnt(0)" ::: "memory");
    }
    asm volatile("s_barrier" ::: "memory");
    const char* Ab = L + cur * 32768;
    const char* Bb = Ab + 16384;
#pragma unroll
    for (int ss = 0; ss < 2; ++ss) {
      bf16x8 af[4], bfv[4];
#pragma unroll
      for (int m = 0; m < 4; ++m) {
        int row = wm * 64 + m * 16 + c;
        int scu = ((ss * 4 + g) ^ row) & 7;
        af[m] = *(const bf16x8*)(Ab + row * 128 + scu * 16);
      }
#pragma unroll
      for (int n = 0; n < 4; ++n) {
        int row = wn * 64 + n * 16 + c;
        int scu = ((ss * 4 + g) ^ row) & 7;
        bfv[n] = *(const bf16x8*)(Bb + row * 128 + scu * 16);
      }
      __builtin_amdgcn_s_setprio(1);
#pragma unroll
      for (int m = 0; m < 4; ++m)
#pragma unroll
        for (int n = 0; n < 4; ++n)
          acc[m][n] = __builtin_amdgcn_mfma_f32_16x16x32_bf16(af[m], bfv[n], acc[m][n], 0, 0, 0);
      __builtin_amdgcn_s_setprio(0);
    }
    asm volatile("s_barrier" ::: "memory");
    cur ^= 1;
  }

  // transpose epilogue through LDS (reuses buffers), k-permuted writes
  u16* CT = smem;                               // [128 d][136 pitch] u16
  __syncthreads();
#pragma unroll
  for (int m = 0; m < 4; ++m)
#pragma unroll
    for (int n = 0; n < 4; ++n) {
      int lcol = wn * 64 + n * 16 + c;
      float bvv = bias[n0 + lcol];
#pragma unroll
      for (int r = 0; r < 4; ++r) {
        int lrow = wm * 64 + m * 16 + g * 4 + r;
        CT[lcol * 136 + lrow] = f2bf(acc[m][n][r] + bvv);
      }
    }
  __syncthreads();
  const int b = m0 >> 11, h = n0 >> 7, s0 = m0 & (Sc - 1);
#pragma unroll
  for (int i = 0; i < 8; ++i) {
    int u = i * 256 + t;
    int d = u >> 4, su = u & 15;
    size_t gbase = ((size_t)((b * Hc + h) * HDc) + d) * Sc + s0;
#pragma unroll
    for (int p2 = 0; p2 < 4; ++p2) {
      int sl = su * 8 + p2 * 2;
      u32 val = (u32)CT[d * 136 + sl] | ((u32)CT[d * 136 + sl + 1] << 16);
      int w6 = sl & 63, blk = sl >> 6;
      int slot = ((w6 >> 5) << 5) | (((w6 >> 2) & 3) << 3) |
                 (((w6 >> 4) & 1) << 2) | (w6 & 3);
      *(u32*)&vout[gbase + blk * 64 + slot] = val;
    }
  }
}

// -------- O-projection GEMM (counted-vmcnt dbuf): fp32 [M,N] to d_out -----
__global__ __launch_bounds__(256) void gemm_out(
    const u16* __restrict__ A, const u16* __restrict__ W,
    const float* __restrict__ bias, float* __restrict__ outp) {
  __shared__ u16 smem[32768];     // 64KB dbuf
  char* L = (char*)smem;
  const int t = threadIdx.x;
  const int w = t >> 6, lane = t & 63, g = lane >> 4, c = lane & 15;
  const int wm = w >> 1, wn = w & 1;
  const int m0 = blockIdx.y * GBM, n0 = blockIdx.x * GBN;

  f32x4 acc[4][4];
#pragma unroll
  for (int m = 0; m < 4; ++m)
#pragma unroll
    for (int n = 0; n < 4; ++n) acc[m][n] = 0.f;

  const u16* sA[4];
  const u16* sB[4];
  int dA[4];
#pragma unroll
  for (int i = 0; i < 4; ++i) {
    int u = i * 256 + t;
    int row = u >> 3, p = u & 7;
    int cu = (p ^ row) & 7;
    sA[i] = A + (size_t)(m0 + row) * Dc + cu * 8;
    sB[i] = W + (size_t)(n0 + row) * Dc + cu * 8;
    dA[i] = (i * 256 + (t & 192)) * 16;
  }
  auto STG = [&](int d) {
#pragma unroll
    for (int i = 0; i < 4; ++i) {
      gload16(sA[i], L + d * 32768 + dA[i]);
      sA[i] += 64;
    }
#pragma unroll
    for (int i = 0; i < 4; ++i) {
      gload16(sB[i], L + d * 32768 + 16384 + dA[i]);
      sB[i] += 64;
    }
  };

  STG(0);
  int cur = 0;
#pragma unroll 1
  for (int s = 0; s < 32; ++s) {
    if (s + 1 < 32) {
      STG(cur ^ 1);
      asm volatile("s_waitcnt vmcnt(8)" ::: "memory");
    } else {
      asm volatile("s_waitcnt vmcnt(0)" ::: "memory");
    }
    asm volatile("s_barrier" ::: "memory");
    const char* Ab = L + cur * 32768;
    const char* Bb = Ab + 16384;
#pragma unroll
    for (int ss = 0; ss < 2; ++ss) {
      bf16x8 af[4], bfv[4];
#pragma unroll
      for (int m = 0; m < 4; ++m) {
        int row = wm * 64 + m * 16 + c;
        int scu = ((ss * 4 + g) ^ row) & 7;
        af[m] = *(const bf16x8*)(Ab + row * 128 + scu * 16);
      }
#pragma unroll
      for (int n = 0; n < 4; ++n) {
        int row = wn * 64 + n * 16 + c;
        int scu = ((ss * 4 + g) ^ row) & 7;
        bfv[n] = *(const bf16x8*)(Bb + row * 128 + scu * 16);
      }
      __builtin_amdgcn_s_setprio(1);
#pragma unroll
      for (int m = 0; m < 4; ++m)
#pragma unroll
        for (int n = 0; n < 4; ++n)
          acc[m][n] = __builtin_amdgcn_mfma_f32_16x16x32_bf16(af[m], bfv[n], acc[m][n], 0, 0, 0);
      __builtin_amdgcn_s_setprio(0);
    }
    asm volatile("s_barrier" ::: "memory");
    cur ^= 1;
  }

#pragma unroll
  for (int m = 0; m < 4; ++m)
#pragma unroll
    for (int n = 0; n < 4; ++n) {
      int col = n0 + wn * 64 + n * 16 + c;
      float bv = bias[col];
#pragma unroll
      for (int r = 0; r < 4; ++r) {
        int row = m0 + wm * 64 + m * 16 + g * 4 + r;
        outp[(size_t)row * Dc + col] = acc[m][n][r] + bv;
      }
    }
}

// ======== attention v10: counted-vmcnt dbuf + per-n QK/SM/PV interleave ====
// 512 blocks (XCD-swz), 256 thr = 4 waves, 32 q/wave. K+V dbuf (64KB).
// Per tile: mask -> STAGE(next) -> vmcnt(16) -> barrier -> interleaved
// {QK(n) MFMA | SM(n) VALU | PV-half MFMA | V-frag ds_reads} -> barrier.
// Per-n restructure shortens the QK->SM->PV serial chain: SM(n) overlaps
// QK(n+1) on the separate VALU pipe; PV(s2) needs only n=2*s2..2*s2+1.
// FP order identical to v9 -> bit-identical output.
__global__ __launch_bounds__(256, 2) void attn_mfma(
    const u16* __restrict__ Q, const u16* __restrict__ K,
    const u16* __restrict__ VT, const float* __restrict__ mask,
    u16* __restrict__ outb) {
  __shared__ u16 Ks[2][64 * 128];   // 16KB each
  __shared__ u16 Vt[2][64 * 128];
  const int t = threadIdx.x, w = t >> 6, lane = t & 63, g = lane >> 4, c = lane & 15;
  const int bid = blockIdx.x;
  const int nid = (bid & 7) * 64 + (bid >> 3);   // 512%8==0 bijective
  const int bh = nid >> 4;                       // head (4 heads/XCD)
  const int q0 = (nid & 15) * 128;               // 128 q-rows per block
  const int bq = bh >> 4, h = bh & 15;
  const u16* Qp = Q + ((size_t)bh << 18);
  const u16* Kp = K + ((size_t)bh << 18);
  const u16* VTp = VT + ((size_t)bh << 18);

  const u16* kSrc[4];
  const u16* vSrc[4];
  int kOff[4], vOff[4];
#pragma unroll
  for (int i = 0; i < 4; ++i) {
    int u = i * 256 + t;
    int row = u >> 4, p = u & 15;
    int cu = (p & 8) | ((p ^ row) & 7);
    kSrc[i] = Kp + (size_t)row * HDc + cu * 8;
    kOff[i] = (i * 256 + (t & 192)) * 16;
    int d = u >> 3, pv = u & 7;
    int cv = (pv ^ d) & 7;
    vSrc[i] = VTp + (size_t)d * Sc + cv * 8;
    vOff[i] = (i * 256 + (t & 192)) * 16;
  }

  auto STAGE = [&](int buf) {
#pragma unroll
    for (int i = 0; i < 4; ++i) {
      gload16(kSrc[i], (char*)Ks[buf] + kOff[i]);
      kSrc[i] += 64 * HDc;
    }
#pragma unroll
    for (int i = 0; i < 4; ++i) {
      gload16(vSrc[i], (char*)Vt[buf] + vOff[i]);
      vSrc[i] += 64;
    }
  };

  // Q fragments for both q-sets (pre-scaled by SCALE*log2e)
  bf16x8 qf0[4], qf1[4];
  {
    int qr0 = q0 + w * 32 + c;
#pragma unroll
    for (int d0 = 0; d0 < 4; ++d0) {
      qf0[d0] = *(const bf16x8*)(Qp + (size_t)qr0 * HDc + d0 * 32 + g * 8);
      qf1[d0] = *(const bf16x8*)(Qp + (size_t)(qr0 + 16) * HDc + d0 * 32 + g * 8);
    }
  }

  f32x4 po0[8], po1[8];
#pragma unroll
  for (int m = 0; m < 8; ++m) { po0[m] = 0.f; po1[m] = 0.f; }
  float lsum0 = 0.f, lsum1 = 0.f;
  const float* mrow0 = mask + ((size_t)bq * Sc + q0 + w * 32 + c) * Sc;
  const float* mrow1 = mrow0 + (size_t)16 * Sc;

  STAGE(0);
  asm volatile("s_waitcnt vmcnt(0)" ::: "memory");
  asm volatile("s_barrier" ::: "memory");
  int cur = 0;

#pragma unroll 1
  for (int kt = 0; kt < 32; ++kt) {
    const int k0 = kt * 64;
    float4 mk0[4], mk1[4];
#pragma unroll
    for (int n = 0; n < 4; ++n) {
      mk0[n] = *(const float4*)(mrow0 + k0 + n * 16 + g * 4);
      mk1[n] = *(const float4*)(mrow1 + k0 + n * 16 + g * 4);
    }
    if (kt + 1 < 32) {
      STAGE(cur ^ 1);
      asm volatile("s_waitcnt vmcnt(16)" ::: "memory");
    } else {
      asm volatile("s_waitcnt vmcnt(8)" ::: "memory");
    }
    asm volatile("s_barrier" ::: "memory");

    const char* Ksb = (const char*)Ks[cur];
    const char* Vtb = (const char*)Vt[cur];

    u32 a01[4], a23[4], b01[4], b23[4];

    // QK(n) + SM(n): 8 MFMAs complete sfr[n]; SM VALU overlaps next QK
    auto QKSM = [&](int n) {
      f32x4 s0v = 0.f, s1v = 0.f;
      int row = n * 16 + c;
#pragma unroll
      for (int ds = 0; ds < 4; ++ds) {
        int cu2 = ds * 4 + g;
        int scu = (cu2 & 8) | ((cu2 ^ row) & 7);
        bf16x8 kf = *(const bf16x8*)(Ksb + row * 256 + scu * 16);
        s0v = __builtin_amdgcn_mfma_f32_16x16x32_bf16(kf, qf0[ds], s0v, 0, 0, 0);
        s1v = __builtin_amdgcn_mfma_f32_16x16x32_bf16(kf, qf1[ds], s1v, 0, 0, 0);
      }
      float p0 = __builtin_amdgcn_exp2f(fmaf(mk0[n].x, LOG2E, s0v[0]));
      float p1 = __builtin_amdgcn_exp2f(fmaf(mk0[n].y, LOG2E, s0v[1]));
      float p2 = __builtin_amdgcn_exp2f(fmaf(mk0[n].z, LOG2E, s0v[2]));
      float p3 = __builtin_amdgcn_exp2f(fmaf(mk0[n].w, LOG2E, s0v[3]));
      lsum0 += (p0 + p1) + (p2 + p3);
      a01[n] = (u32)f2bf(p0) | ((u32)f2bf(p1) << 16);
      a23[n] = (u32)f2bf(p2) | ((u32)f2bf(p3) << 16);
      float r0 = __builtin_amdgcn_exp2f(fmaf(mk1[n].x, LOG2E, s1v[0]));
      float r1 = __builtin_amdgcn_exp2f(fmaf(mk1[n].y, LOG2E, s1v[1]));
      float r2 = __builtin_amdgcn_exp2f(fmaf(mk1[n].z, LOG2E, s1v[2]));
      float r3 = __builtin_amdgcn_exp2f(fmaf(mk1[n].w, LOG2E, s1v[3]));
      lsum1 += (r0 + r1) + (r2 + r3);
      b01[n] = (u32)f2bf(r0) | ((u32)f2bf(r1) << 16);
      b23[n] = (u32)f2bf(r2) | ((u32)f2bf(r3) << 16);
    };

    auto VLOAD = [&](int s2, bf16x8* vfh) {
#pragma unroll
      for (int m = 0; m < 8; ++m) {
        int d = m * 16 + c;
        int scuv = ((s2 * 4 + g) ^ (d & 7)) & 7;
        vfh[m] = *(const bf16x8*)(Vtb + d * 128 + scuv * 16);
      }
    };

    auto PV = [&](const bf16x8* vfh, int s2) {
      uint4 pw0, pw1;
      pw0.x = a01[s2 * 2]; pw0.y = a23[s2 * 2];
      pw0.z = a01[s2 * 2 + 1]; pw0.w = a23[s2 * 2 + 1];
      pw1.x = b01[s2 * 2]; pw1.y = b23[s2 * 2];
      pw1.z = b01[s2 * 2 + 1]; pw1.w = b23[s2 * 2 + 1];
      bf16x8 pf0 = __builtin_bit_cast(bf16x8, pw0);
      bf16x8 pf1 = __builtin_bit_cast(bf16x8, pw1);
#pragma unroll
      for (int m = 0; m < 8; ++m) {
        po0[m] = __builtin_amdgcn_mfma_f32_16x16x32_bf16(vfh[m], pf0, po0[m], 0, 0, 0);
        po1[m] = __builtin_amdgcn_mfma_f32_16x16x32_bf16(vfh[m], pf1, po1[m], 0, 0, 0);
      }
    };

    __builtin_amdgcn_s_setprio(1);
    bf16x8 vfa[8], vfb[8];
    QKSM(0);
    VLOAD(0, vfa);                 // V s2=0 reads hide under QK(1)
    QKSM(1);
    PV(vfa, 0);                    // needs only n=0,1
    QKSM(2);
    VLOAD(1, vfb);                 // V s2=1 reads hide under QK(3)
    QKSM(3);
    PV(vfb, 1);
    __builtin_amdgcn_s_setprio(0);

    asm volatile("s_barrier" ::: "memory");
    cur ^= 1;
  }

  // final l reduction (lanes c, c+16, c+32, c+48 hold partials of same q)
  lsum0 += __shfl_xor(lsum0, 16, 64);
  lsum0 += __shfl_xor(lsum0, 32, 64);
  lsum1 += __shfl_xor(lsum1, 16, 64);
  lsum1 += __shfl_xor(lsum1, 32, 64);
  const float rl0 = 1.0f / lsum0;
  const float rl1 = 1.0f / lsum1;
  const int qg0 = q0 + w * 32 + c;
  u16* ob0 = outb + ((size_t)(bq * Sc + qg0)) * Dc + h * HDc;
  u16* ob1 = ob0 + (size_t)16 * Dc;
#pragma unroll
  for (int m = 0; m < 8; ++m) {
    ushort4 o4;
    o4.x = f2bf(po0[m][0] * rl0);
    o4.y = f2bf(po0[m][1] * rl0);
    o4.z = f2bf(po0[m][2] * rl0);
    o4.w = f2bf(po0[m][3] * rl0);
    *(ushort4*)(ob0 + m * 16 + g * 4) = o4;
    ushort4 o5;
    o5.x = f2bf(po1[m][0] * rl1);
    o5.y = f2bf(po1[m][1] * rl1);
    o5.z = f2bf(po1[m][2] * rl1);
    o5.w = f2bf(po1[m][3] * rl1);
    *(ushort4*)(ob1 + m * 16 + g * 4) = o5;
  }
}

// ---------------- launch ----------------
extern "C" void kernel_launch(void* const* d_in, const int* in_sizes, int n_in,
                              void* d_out, int out_size, void* d_ws,
                              size_t ws_size, hipStream_t stream) {
  const float* hs   = (const float*)d_in[0];
  const float* mask = (const float*)d_in[1];
  const float* Wq   = (const float*)d_in[2];
  const float* bqp  = (const float*)d_in[3];
  const float* Wk   = (const float*)d_in[4];
  const float* bkp  = (const float*)d_in[5];
  const float* Wv   = (const float*)d_in[6];
  const float* bvp  = (const float*)d_in[7];
  const float* Wo   = (const float*)d_in[8];
  const float* bop  = (const float*)d_in[9];

  u16* Xb  = (u16*)d_ws;                 // [4096][2048] bf16
  u16* Wqb = Xb + (size_t)Mc * Dc;
  u16* Wkb = Wqb + (size_t)Dc * Dc;
  u16* Wvb = Wkb + (size_t)Dc * Dc;
  u16* Wob = Wvb + (size_t)Dc * Dc;
  u16* qb  = Wob + (size_t)Dc * Dc;      // [B,H,S,HD] bf16 (scaled SCALE*log2e)
  u16* kb  = qb + (size_t)Mc * Dc;       // [B,H,S,HD] bf16
  u16* vtb = kb + (size_t)Mc * Dc;       // [B,H,HD,S] bf16, k-permuted /32
  u16* ab  = vtb + (size_t)Mc * Dc;      // [B,S,D] bf16

  const int nh4 = Mc * Dc / 4;
  const int nw4 = Dc * Dc / 4;
  cvt5<<<dim3((nh4 + 4 * nw4) / 256), dim3(256), 0, stream>>>(
      hs, Xb, nh4, Wq, Wqb, nw4, Wk, Wkb, nw4, Wv, Wvb, nw4, Wo, Wob, nw4);

  qk_gemm8<<<dim3(Dc / 256, Mc / 256, 2), dim3(512), 0, stream>>>(
      Xb, Wqb, Wkb, bqp, bkp, qb, kb);
  v_gemm<<<dim3(Dc / GBN, Mc / GBM), dim3(256), 0, stream>>>(
      Xb, Wvb, bvp, vtb);
  attn_mfma<<<dim3(512), dim3(256), 0, stream>>>(qb, kb, vtb, mask, ab);
  gemm_out<<<dim3(Dc / GBN, Mc / GBM), dim3(256), 0, stream>>>(
      ab, Wob, bop, (float*)d_out);
}

// Round 18
// 282.545 us; speedup vs baseline: 1.0342x; 1.0342x over previous
//
#include <hip/hip_runtime.h>
#include <hip/hip_bf16.h>
#include <math.h>

typedef unsigned short u16;
typedef unsigned int u32;
typedef __attribute__((ext_vector_type(8))) short bf16x8;   // 8 bf16 = 4 VGPRs
typedef __attribute__((ext_vector_type(4))) float f32x4;

constexpr int Bc = 2, Sc = 2048, Dc = 2048, Hc = 16, HDc = 128;
constexpr int Mc = Bc * Sc;                     // 4096
constexpr float SCALE = 0.08838834764831845f;   // 1/sqrt(128)
constexpr float LOG2E = 1.4426950408889634f;

__device__ inline u16 f2bf(float f) {
  __hip_bfloat16 h = __float2bfloat16(f);
  return __builtin_bit_cast(u16, h);
}

typedef const __attribute__((address_space(1))) u32 glb_u32;
typedef __attribute__((address_space(3))) u32 lds_u32;
__device__ inline void gload16(const void* g, void* l) {
  // async global->LDS, 16B/lane; LDS dest is wave-uniform base + lane*16
  __builtin_amdgcn_global_load_lds((glb_u32*)g, (lds_u32*)l, 16, 0, 0);
}

// ---------------- fp32 -> bf16 convert (hidden + 4 weights) ----------------
__global__ __launch_bounds__(256) void cvt5(
    const float* __restrict__ s0, u16* __restrict__ d0, int n0,
    const float* __restrict__ s1, u16* __restrict__ d1, int n1,
    const float* __restrict__ s2, u16* __restrict__ d2, int n2,
    const float* __restrict__ s3, u16* __restrict__ d3, int n3,
    const float* __restrict__ s4, u16* __restrict__ d4, int n4) {
  int i = blockIdx.x * 256 + threadIdx.x;   // float4 index
  const float* s; u16* d;
  if (i < n0) { s = s0; d = d0; }
  else { i -= n0;
    if (i < n1) { s = s1; d = d1; }
    else { i -= n1;
      if (i < n2) { s = s2; d = d2; }
      else { i -= n2;
        if (i < n3) { s = s3; d = d3; }
        else { i -= n3;
          if (i >= n4) return;
          s = s4; d = d4; } } } }
  float4 v = reinterpret_cast<const float4*>(s)[i];
  ushort4 o;
  o.x = f2bf(v.x); o.y = f2bf(v.y); o.z = f2bf(v.z); o.w = f2bf(v.w);
  reinterpret_cast<ushort4*>(d)[i] = o;
}

// ======== Q+K fused GEMM, 256x256 tile, 8 waves, counted-vmcnt dbuf =======
__global__ __launch_bounds__(512, 2) void qk_gemm8(
    const u16* __restrict__ A, const u16* __restrict__ Wq,
    const u16* __restrict__ Wk, const float* __restrict__ bq,
    const float* __restrict__ bk, u16* __restrict__ qout,
    u16* __restrict__ kout) {
  __shared__ u16 lds[65536];      // 128 KB
  char* L = (char*)lds;
  const int t = threadIdx.x, w = t >> 6, lane = t & 63, g = lane >> 4, c = lane & 15;
  const int wm = w >> 2, wn = w & 3;           // 2M x 4N wave grid
  const int m0 = blockIdx.y * 256, n0 = blockIdx.x * 256;
  const int z = blockIdx.z;
  const u16* W = z ? Wk : Wq;
  const float* bias = z ? bk : bq;
  const float scale = z ? 1.0f : SCALE * LOG2E;

  f32x4 acc[8][4];
#pragma unroll
  for (int m = 0; m < 8; ++m)
#pragma unroll
    for (int n = 0; n < 4; ++n) acc[m][n] = 0.f;

  const u16* sPtr[8];
  int dOff[8];
#pragma unroll
  for (int i = 0; i < 8; ++i) {
    int i2 = i & 3;
    int u = i2 * 512 + t;
    int row = u >> 3, p = u & 7;
    int cu = (p ^ row) & 7;
    const u16* base = (i < 4) ? (A + (size_t)(m0 + row) * Dc)
                              : (W + (size_t)(n0 + row) * Dc);
    sPtr[i] = base + cu * 8;
    dOff[i] = ((i >= 4) ? 32768 : 0) + (i2 >> 1) * 16384 +
              ((i2 & 1) * 512 + (t & 448)) * 16;
  }

  auto STAGE = [&](int d) {
#pragma unroll
    for (int i = 0; i < 8; ++i) {
      gload16(sPtr[i], L + d * 65536 + dOff[i]);
      sPtr[i] += 64;
    }
  };

  STAGE(0);
  asm volatile("s_waitcnt vmcnt(0)" ::: "memory");
  asm volatile("s_barrier" ::: "memory");

  int cur = 0;
  const char* AbBase = L + wm * 16384;
  const char* BbBase = L + 32768 + (wn >> 1) * 16384;
  const int rB0 = (wn & 1) * 64;

#pragma unroll 1
  for (int s = 0; s < 32; ++s) {
    if (s + 1 < 32) {
      STAGE(cur ^ 1);
      asm volatile("s_waitcnt vmcnt(8)" ::: "memory");
    } else {
      asm volatile("s_waitcnt vmcnt(0)" ::: "memory");
    }
    asm volatile("s_barrier" ::: "memory");

    const char* Ab = AbBase + cur * 65536;
    const char* Bb = BbBase + cur * 65536;
#pragma unroll
    for (int mh = 0; mh < 2; ++mh)
#pragma unroll
      for (int ks = 0; ks < 2; ++ks) {
        bf16x8 af[4], bf[4];
#pragma unroll
        for (int m4 = 0; m4 < 4; ++m4) {
          int row = (mh * 4 + m4) * 16 + c;
          af[m4] = *(const bf16x8*)(Ab + row * 128 + (((ks * 4 + g) ^ row) & 7) * 16);
        }
#pragma unroll
        for (int n = 0; n < 4; ++n) {
          int row = rB0 + n * 16 + c;
          bf[n] = *(const bf16x8*)(Bb + row * 128 + (((ks * 4 + g) ^ row) & 7) * 16);
        }
        __builtin_amdgcn_s_setprio(1);
#pragma unroll
        for (int m4 = 0; m4 < 4; ++m4)
#pragma unroll
          for (int n = 0; n < 4; ++n)
            acc[mh * 4 + m4][n] =
                __builtin_amdgcn_mfma_f32_16x16x32_bf16(af[m4], bf[n], acc[mh * 4 + m4][n], 0, 0, 0);
        __builtin_amdgcn_s_setprio(0);
      }

    asm volatile("s_barrier" ::: "memory");
    cur ^= 1;
  }

  u16* outp = z ? kout : qout;
#pragma unroll
  for (int n = 0; n < 4; ++n) {
    int col = n0 + wn * 64 + n * 16 + c;
    float bvv = bias[col];
    int h = col >> 7, d = col & (HDc - 1);
#pragma unroll
    for (int m = 0; m < 8; ++m)
#pragma unroll
      for (int r = 0; r < 4; ++r) {
        int row = m0 + wm * 128 + m * 16 + g * 4 + r;
        int b = row >> 11, si = row & (Sc - 1);
        outp[((size_t)((b * Hc + h) * Sc + si)) * HDc + d] =
            f2bf((acc[m][n][r] + bvv) * scale);
      }
  }
}

// ---------------- V GEMM (128², MODE2: transpose + k-perm) ----------------
constexpr int GBM = 128, GBN = 128, GBK = 64;

__global__ __launch_bounds__(256) void v_gemm(
    const u16* __restrict__ A, const u16* __restrict__ W,
    const float* __restrict__ bias, u16* __restrict__ vout) {
  __shared__ u16 smem[17408];
  u16* As = smem;
  u16* Bs = smem + 8192;
  char* Asb = (char*)As;
  char* Bsb = (char*)Bs;
  const int t = threadIdx.x;
  const int w = t >> 6, lane = t & 63, g = lane >> 4, c = lane & 15;
  const int wm = w >> 1, wn = w & 1;
  const int m0 = blockIdx.y * GBM, n0 = blockIdx.x * GBN;

  f32x4 acc[4][4];
#pragma unroll
  for (int m = 0; m < 4; ++m)
#pragma unroll
    for (int n = 0; n < 4; ++n) acc[m][n] = 0.f;

  for (int k0 = 0; k0 < Dc; k0 += GBK) {
#pragma unroll
    for (int i = 0; i < 4; ++i) {
      int u = i * 256 + t;
      int row = u >> 3, p = u & 7;
      int cu = (p ^ row) & 7;
      int ub = i * 256 + (t & 192);
      gload16(A + (size_t)(m0 + row) * Dc + k0 + cu * 8, Asb + ub * 16);
      gload16(W + (size_t)(n0 + row) * Dc + k0 + cu * 8, Bsb + ub * 16);
    }
    __syncthreads();
#pragma unroll
    for (int s = 0; s < 2; ++s) {
      bf16x8 af[4], bfv[4];
#pragma unroll
      for (int m = 0; m < 4; ++m) {
        int row = wm * 64 + m * 16 + c;
        int scu = ((s * 4 + g) ^ row) & 7;
        af[m] = *(const bf16x8*)(Asb + row * 128 + scu * 16);
      }
#pragma unroll
      for (int n = 0; n < 4; ++n) {
        int row = wn * 64 + n * 16 + c;
        int scu = ((s * 4 + g) ^ row) & 7;
        bfv[n] = *(const bf16x8*)(Bsb + row * 128 + scu * 16);
      }
#pragma unroll
      for (int m = 0; m < 4; ++m)
#pragma unroll
        for (int n = 0; n < 4; ++n)
          acc[m][n] = __builtin_amdgcn_mfma_f32_16x16x32_bf16(af[m], bfv[n], acc[m][n], 0, 0, 0);
    }
    __syncthreads();
  }

  u16* CT = smem;                               // [128 d][136 pitch] u16
  __syncthreads();
#pragma unroll
  for (int m = 0; m < 4; ++m)
#pragma unroll
    for (int n = 0; n < 4; ++n) {
      int lcol = wn * 64 + n * 16 + c;
      float bvv = bias[n0 + lcol];
#pragma unroll
      for (int r = 0; r < 4; ++r) {
        int lrow = wm * 64 + m * 16 + g * 4 + r;
        CT[lcol * 136 + lrow] = f2bf(acc[m][n][r] + bvv);
      }
    }
  __syncthreads();
  const int b = m0 >> 11, h = n0 >> 7, s0 = m0 & (Sc - 1);
#pragma unroll
  for (int i = 0; i < 8; ++i) {
    int u = i * 256 + t;
    int d = u >> 4, su = u & 15;
    size_t gbase = ((size_t)((b * Hc + h) * HDc) + d) * Sc + s0;
#pragma unroll
    for (int p2 = 0; p2 < 4; ++p2) {
      int sl = su * 8 + p2 * 2;
      u32 val = (u32)CT[d * 136 + sl] | ((u32)CT[d * 136 + sl + 1] << 16);
      int w6 = sl & 63, blk = sl >> 6;
      int slot = ((w6 >> 5) << 5) | (((w6 >> 2) & 3) << 3) |
                 (((w6 >> 4) & 1) << 2) | (w6 & 3);
      *(u32*)&vout[gbase + blk * 64 + slot] = val;
    }
  }
}

// ---------------- O-projection GEMM: fp32 [M,N] to d_out ----------------
__global__ __launch_bounds__(256) void gemm_out(
    const u16* __restrict__ A, const u16* __restrict__ W,
    const float* __restrict__ bias, float* __restrict__ outp) {
  __shared__ u16 smem[16384];
  u16* As = smem;
  u16* Bs = smem + 8192;
  char* Asb = (char*)As;
  char* Bsb = (char*)Bs;
  const int t = threadIdx.x;
  const int w = t >> 6, lane = t & 63, g = lane >> 4, c = lane & 15;
  const int wm = w >> 1, wn = w & 1;
  const int m0 = blockIdx.y * GBM, n0 = blockIdx.x * GBN;

  f32x4 acc[4][4];
#pragma unroll
  for (int m = 0; m < 4; ++m)
#pragma unroll
    for (int n = 0; n < 4; ++n) acc[m][n] = 0.f;

  for (int k0 = 0; k0 < Dc; k0 += GBK) {
#pragma unroll
    for (int i = 0; i < 4; ++i) {
      int u = i * 256 + t;
      int row = u >> 3, p = u & 7;
      int cu = (p ^ row) & 7;
      int ub = i * 256 + (t & 192);
      gload16(A + (size_t)(m0 + row) * Dc + k0 + cu * 8, Asb + ub * 16);
      gload16(W + (size_t)(n0 + row) * Dc + k0 + cu * 8, Bsb + ub * 16);
    }
    __syncthreads();
#pragma unroll
    for (int s = 0; s < 2; ++s) {
      bf16x8 af[4], bfv[4];
#pragma unroll
      for (int m = 0; m < 4; ++m) {
        int row = wm * 64 + m * 16 + c;
        int scu = ((s * 4 + g) ^ row) & 7;
        af[m] = *(const bf16x8*)(Asb + row * 128 + scu * 16);
      }
#pragma unroll
      for (int n = 0; n < 4; ++n) {
        int row = wn * 64 + n * 16 + c;
        int scu = ((s * 4 + g) ^ row) & 7;
        bfv[n] = *(const bf16x8*)(Bsb + row * 128 + scu * 16);
      }
#pragma unroll
      for (int m = 0; m < 4; ++m)
#pragma unroll
        for (int n = 0; n < 4; ++n)
          acc[m][n] = __builtin_amdgcn_mfma_f32_16x16x32_bf16(af[m], bfv[n], acc[m][n], 0, 0, 0);
    }
    __syncthreads();
  }

#pragma unroll
  for (int m = 0; m < 4; ++m)
#pragma unroll
    for (int n = 0; n < 4; ++n) {
      int col = n0 + wn * 64 + n * 16 + c;
      float bv = bias[col];
#pragma unroll
      for (int r = 0; r < 4; ++r) {
        int row = m0 + wm * 64 + m * 16 + g * 4 + r;
        outp[(size_t)row * Dc + col] = acc[m][n][r] + bv;
      }
    }
}

// ======== attention v9: counted-vmcnt double-buffered pipeline ========
// 512 blocks (XCD-swz, 4 heads/XCD), 256 thr = 4 waves, 32 q/wave (two
// 16-q sets) -> 128 q/block. K+V double-buffered (64KB -> 2 blocks/CU,
// 8 waves/CU). Per tile: mask loads -> STAGE(next) -> vmcnt(16) [drains
// only tile-kt staging; next tile's loads stay in flight a full compute
// phase] -> raw s_barrier -> compute -> raw s_barrier. Swapped QK^T,
// in-lane P pack (k-permuted V), exp2 softmax.
__global__ __launch_bounds__(256) void attn_mfma(
    const u16* __restrict__ Q, const u16* __restrict__ K,
    const u16* __restrict__ VT, const float* __restrict__ mask,
    u16* __restrict__ outb) {
  __shared__ u16 Ks[2][64 * 128];   // 16KB each
  __shared__ u16 Vt[2][64 * 128];
  const int t = threadIdx.x, w = t >> 6, lane = t & 63, g = lane >> 4, c = lane & 15;
  const int bid = blockIdx.x;
  const int nid = (bid & 7) * 64 + (bid >> 3);   // 512%8==0 bijective
  const int bh = nid >> 4;                       // head (4 heads/XCD)
  const int q0 = (nid & 15) * 128;               // 128 q-rows per block
  const int bq = bh >> 4, h = bh & 15;
  const u16* Qp = Q + ((size_t)bh << 18);
  const u16* Kp = K + ((size_t)bh << 18);
  const u16* VTp = VT + ((size_t)bh << 18);

  // per-thread staging sources (4 K units + 4 V units), advanced per tile
  const u16* kSrc[4];
  const u16* vSrc[4];
  int kOff[4], vOff[4];
#pragma unroll
  for (int i = 0; i < 4; ++i) {
    int u = i * 256 + t;
    int row = u >> 4, p = u & 15;
    int cu = (p & 8) | ((p ^ row) & 7);
    kSrc[i] = Kp + (size_t)row * HDc + cu * 8;
    kOff[i] = (i * 256 + (t & 192)) * 16;
    int d = u >> 3, pv = u & 7;
    int cv = (pv ^ d) & 7;
    vSrc[i] = VTp + (size_t)d * Sc + cv * 8;
    vOff[i] = (i * 256 + (t & 192)) * 16;
  }

  auto STAGE = [&](int buf) {
#pragma unroll
    for (int i = 0; i < 4; ++i) {
      gload16(kSrc[i], (char*)Ks[buf] + kOff[i]);
      kSrc[i] += 64 * HDc;
    }
#pragma unroll
    for (int i = 0; i < 4; ++i) {
      gload16(vSrc[i], (char*)Vt[buf] + vOff[i]);
      vSrc[i] += 64;
    }
  };

  // Q fragments for both q-sets (pre-scaled by SCALE*log2e)
  bf16x8 qf0[4], qf1[4];
  {
    int qr0 = q0 + w * 32 + c;
#pragma unroll
    for (int d0 = 0; d0 < 4; ++d0) {
      qf0[d0] = *(const bf16x8*)(Qp + (size_t)qr0 * HDc + d0 * 32 + g * 8);
      qf1[d0] = *(const bf16x8*)(Qp + (size_t)(qr0 + 16) * HDc + d0 * 32 + g * 8);
    }
  }

  f32x4 po0[8], po1[8];
#pragma unroll
  for (int m = 0; m < 8; ++m) { po0[m] = 0.f; po1[m] = 0.f; }
  float lsum0 = 0.f, lsum1 = 0.f;
  const float* mrow0 = mask + ((size_t)bq * Sc + q0 + w * 32 + c) * Sc;
  const float* mrow1 = mrow0 + (size_t)16 * Sc;

  STAGE(0);
  asm volatile("s_waitcnt vmcnt(0)" ::: "memory");
  asm volatile("s_barrier" ::: "memory");
  int cur = 0;

#pragma unroll 1
  for (int kt = 0; kt < 32; ++kt) {
    const int k0 = kt * 64;
    // mask loads for THIS tile (8 dwordx4)
    float4 mk0[4], mk1[4];
#pragma unroll
    for (int n = 0; n < 4; ++n) {
      mk0[n] = *(const float4*)(mrow0 + k0 + n * 16 + g * 4);
      mk1[n] = *(const float4*)(mrow1 + k0 + n * 16 + g * 4);
    }
    if (kt + 1 < 32) {
      STAGE(cur ^ 1);                          // prefetch tile kt+1
      // outstanding <= stage_kt(8,oldest) + mask(8) + stage_kt+1(8) = 24;
      // drain to 16 -> exactly stage_kt done; prefetch stays in flight
      asm volatile("s_waitcnt vmcnt(16)" ::: "memory");
    } else {
      asm volatile("s_waitcnt vmcnt(8)" ::: "memory");   // drain stage_kt
    }
    asm volatile("s_barrier" ::: "memory");    // tile-kt K/V visible to all

    const char* Ksb = (const char*)Ks[cur];
    const char* Vtb = (const char*)Vt[cur];

    // QK^T (swapped): S^T[k][q]; each kf shared by both q-sets
    f32x4 sfr0[4], sfr1[4];
#pragma unroll
    for (int n = 0; n < 4; ++n) { sfr0[n] = 0.f; sfr1[n] = 0.f; }
    __builtin_amdgcn_s_setprio(1);
#pragma unroll
    for (int ds = 0; ds < 4; ++ds)
#pragma unroll
      for (int n = 0; n < 4; ++n) {
        int row = n * 16 + c;
        int cu = ds * 4 + g;
        int scu = (cu & 8) | ((cu ^ row) & 7);
        bf16x8 kf = *(const bf16x8*)(Ksb + row * 256 + scu * 16);
        sfr0[n] = __builtin_amdgcn_mfma_f32_16x16x32_bf16(kf, qf0[ds], sfr0[n], 0, 0, 0);
        sfr1[n] = __builtin_amdgcn_mfma_f32_16x16x32_bf16(kf, qf1[ds], sfr1[n], 0, 0, 0);
      }
    __builtin_amdgcn_s_setprio(0);

    // softmax: p = exp2(s + mask*log2e); in-lane pack to PV B-operand
    u32 a01[4], a23[4], b01[4], b23[4];
#pragma unroll
    for (int n = 0; n < 4; ++n) {
      float p0 = __builtin_amdgcn_exp2f(fmaf(mk0[n].x, LOG2E, sfr0[n][0]));
      float p1 = __builtin_amdgcn_exp2f(fmaf(mk0[n].y, LOG2E, sfr0[n][1]));
      float p2 = __builtin_amdgcn_exp2f(fmaf(mk0[n].z, LOG2E, sfr0[n][2]));
      float p3 = __builtin_amdgcn_exp2f(fmaf(mk0[n].w, LOG2E, sfr0[n][3]));
      lsum0 += (p0 + p1) + (p2 + p3);
      a01[n] = (u32)f2bf(p0) | ((u32)f2bf(p1) << 16);
      a23[n] = (u32)f2bf(p2) | ((u32)f2bf(p3) << 16);
      float r0 = __builtin_amdgcn_exp2f(fmaf(mk1[n].x, LOG2E, sfr1[n][0]));
      float r1 = __builtin_amdgcn_exp2f(fmaf(mk1[n].y, LOG2E, sfr1[n][1]));
      float r2 = __builtin_amdgcn_exp2f(fmaf(mk1[n].z, LOG2E, sfr1[n][2]));
      float r3 = __builtin_amdgcn_exp2f(fmaf(mk1[n].w, LOG2E, sfr1[n][3]));
      lsum1 += (r0 + r1) + (r2 + r3);
      b01[n] = (u32)f2bf(r0) | ((u32)f2bf(r1) << 16);
      b23[n] = (u32)f2bf(r2) | ((u32)f2bf(r3) << 16);
    }

    // PV: O^T += V^T * P^T; each vf shared by both q-sets
    __builtin_amdgcn_s_setprio(1);
#pragma unroll
    for (int s2 = 0; s2 < 2; ++s2) {
      uint4 pw0, pw1;
      pw0.x = a01[s2 * 2]; pw0.y = a23[s2 * 2];
      pw0.z = a01[s2 * 2 + 1]; pw0.w = a23[s2 * 2 + 1];
      pw1.x = b01[s2 * 2]; pw1.y = b23[s2 * 2];
      pw1.z = b01[s2 * 2 + 1]; pw1.w = b23[s2 * 2 + 1];
      bf16x8 pf0 = __builtin_bit_cast(bf16x8, pw0);
      bf16x8 pf1 = __builtin_bit_cast(bf16x8, pw1);
#pragma unroll
      for (int m = 0; m < 8; ++m) {
        int d = m * 16 + c;
        int scuv = ((s2 * 4 + g) ^ (d & 7)) & 7;
        bf16x8 vf = *(const bf16x8*)(Vtb + d * 128 + scuv * 16);
        po0[m] = __builtin_amdgcn_mfma_f32_16x16x32_bf16(vf, pf0, po0[m], 0, 0, 0);
        po1[m] = __builtin_amdgcn_mfma_f32_16x16x32_bf16(vf, pf1, po1[m], 0, 0, 0);
      }
    }
    __builtin_amdgcn_s_setprio(0);
    // all LDS reads consumed by MFMAs above (compiler lgkmcnt waits) ->
    // barrier only orders reads-done vs next overwrite; no vmcnt drain
    asm volatile("s_barrier" ::: "memory");
    cur ^= 1;
  }

  // final l reduction (lanes c, c+16, c+32, c+48 hold partials of same q)
  lsum0 += __shfl_xor(lsum0, 16, 64);
  lsum0 += __shfl_xor(lsum0, 32, 64);
  lsum1 += __shfl_xor(lsum1, 16, 64);
  lsum1 += __shfl_xor(lsum1, 32, 64);
  const float rl0 = 1.0f / lsum0;
  const float rl1 = 1.0f / lsum1;
  const int qg0 = q0 + w * 32 + c;
  u16* ob0 = outb + ((size_t)(bq * Sc + qg0)) * Dc + h * HDc;
  u16* ob1 = ob0 + (size_t)16 * Dc;
#pragma unroll
  for (int m = 0; m < 8; ++m) {
    ushort4 o4;
    o4.x = f2bf(po0[m][0] * rl0);
    o4.y = f2bf(po0[m][1] * rl0);
    o4.z = f2bf(po0[m][2] * rl0);
    o4.w = f2bf(po0[m][3] * rl0);
    *(ushort4*)(ob0 + m * 16 + g * 4) = o4;
    ushort4 o5;
    o5.x = f2bf(po1[m][0] * rl1);
    o5.y = f2bf(po1[m][1] * rl1);
    o5.z = f2bf(po1[m][2] * rl1);
    o5.w = f2bf(po1[m][3] * rl1);
    *(ushort4*)(ob1 + m * 16 + g * 4) = o5;
  }
}

// ---------------- launch ----------------
extern "C" void kernel_launch(void* const* d_in, const int* in_sizes, int n_in,
                              void* d_out, int out_size, void* d_ws,
                              size_t ws_size, hipStream_t stream) {
  const float* hs   = (const float*)d_in[0];
  const float* mask = (const float*)d_in[1];
  const float* Wq   = (const float*)d_in[2];
  const float* bqp  = (const float*)d_in[3];
  const float* Wk   = (const float*)d_in[4];
  const float* bkp  = (const float*)d_in[5];
  const float* Wv   = (const float*)d_in[6];
  const float* bvp  = (const float*)d_in[7];
  const float* Wo   = (const float*)d_in[8];
  const float* bop  = (const float*)d_in[9];

  u16* Xb  = (u16*)d_ws;                 // [4096][2048] bf16
  u16* Wqb = Xb + (size_t)Mc * Dc;
  u16* Wkb = Wqb + (size_t)Dc * Dc;
  u16* Wvb = Wkb + (size_t)Dc * Dc;
  u16* Wob = Wvb + (size_t)Dc * Dc;
  u16* qb  = Wob + (size_t)Dc * Dc;      // [B,H,S,HD] bf16 (scaled SCALE*log2e)
  u16* kb  = qb + (size_t)Mc * Dc;       // [B,H,S,HD] bf16
  u16* vtb = kb + (size_t)Mc * Dc;       // [B,H,HD,S] bf16, k-permuted /32
  u16* ab  = vtb + (size_t)Mc * Dc;      // [B,S,D] bf16

  const int nh4 = Mc * Dc / 4;
  const int nw4 = Dc * Dc / 4;
  cvt5<<<dim3((nh4 + 4 * nw4) / 256), dim3(256), 0, stream>>>(
      hs, Xb, nh4, Wq, Wqb, nw4, Wk, Wkb, nw4, Wv, Wvb, nw4, Wo, Wob, nw4);

  qk_gemm8<<<dim3(Dc / 256, Mc / 256, 2), dim3(512), 0, stream>>>(
      Xb, Wqb, Wkb, bqp, bkp, qb, kb);
  v_gemm<<<dim3(Dc / GBN, Mc / GBM), dim3(256), 0, stream>>>(
      Xb, Wvb, bvp, vtb);
  attn_mfma<<<dim3(512), dim3(256), 0, stream>>>(qb, kb, vtb, mask, ab);
  gemm_out<<<dim3(Dc / GBN, Mc / GBM), dim3(256), 0, stream>>>(
      ab, Wob, bop, (float*)d_out);
}

// Round 19
// 278.863 us; speedup vs baseline: 1.0478x; 1.0132x over previous
//
#include <hip/hip_runtime.h>
#include <hip/hip_bf16.h>
#include <math.h>

typedef unsigned short u16;
typedef unsigned int u32;
typedef __attribute__((ext_vector_type(8))) short bf16x8;   // 8 bf16 = 4 VGPRs
typedef __attribute__((ext_vector_type(4))) float f32x4;

constexpr int Bc = 2, Sc = 2048, Dc = 2048, Hc = 16, HDc = 128;
constexpr int Mc = Bc * Sc;                     // 4096
constexpr float SCALE = 0.08838834764831845f;   // 1/sqrt(128)
constexpr float LOG2E = 1.4426950408889634f;

__device__ inline u16 f2bf(float f) {
  __hip_bfloat16 h = __float2bfloat16(f);
  return __builtin_bit_cast(u16, h);
}

typedef const __attribute__((address_space(1))) u32 glb_u32;
typedef __attribute__((address_space(3))) u32 lds_u32;
__device__ inline void gload16(const void* g, void* l) {
  // async global->LDS, 16B/lane; LDS dest is wave-uniform base + lane*16
  __builtin_amdgcn_global_load_lds((glb_u32*)g, (lds_u32*)l, 16, 0, 0);
}

// ---------------- fp32 -> bf16 convert (hidden + 4 weights) ----------------
__global__ __launch_bounds__(256) void cvt5(
    const float* __restrict__ s0, u16* __restrict__ d0, int n0,
    const float* __restrict__ s1, u16* __restrict__ d1, int n1,
    const float* __restrict__ s2, u16* __restrict__ d2, int n2,
    const float* __restrict__ s3, u16* __restrict__ d3, int n3,
    const float* __restrict__ s4, u16* __restrict__ d4, int n4) {
  int i = blockIdx.x * 256 + threadIdx.x;   // float4 index
  const float* s; u16* d;
  if (i < n0) { s = s0; d = d0; }
  else { i -= n0;
    if (i < n1) { s = s1; d = d1; }
    else { i -= n1;
      if (i < n2) { s = s2; d = d2; }
      else { i -= n2;
        if (i < n3) { s = s3; d = d3; }
        else { i -= n3;
          if (i >= n4) return;
          s = s4; d = d4; } } } }
  float4 v = reinterpret_cast<const float4*>(s)[i];
  ushort4 o;
  o.x = f2bf(v.x); o.y = f2bf(v.y); o.z = f2bf(v.z); o.w = f2bf(v.w);
  reinterpret_cast<ushort4*>(d)[i] = o;
}

// ======== Q+K fused GEMM, 256x256 tile, 8 waves, counted-vmcnt dbuf =======
__global__ __launch_bounds__(512, 2) void qk_gemm8(
    const u16* __restrict__ A, const u16* __restrict__ Wq,
    const u16* __restrict__ Wk, const float* __restrict__ bq,
    const float* __restrict__ bk, u16* __restrict__ qout,
    u16* __restrict__ kout) {
  __shared__ u16 lds[65536];      // 128 KB
  char* L = (char*)lds;
  const int t = threadIdx.x, w = t >> 6, lane = t & 63, g = lane >> 4, c = lane & 15;
  const int wm = w >> 2, wn = w & 3;           // 2M x 4N wave grid
  const int m0 = blockIdx.y * 256, n0 = blockIdx.x * 256;
  const int z = blockIdx.z;
  const u16* W = z ? Wk : Wq;
  const float* bias = z ? bk : bq;
  const float scale = z ? 1.0f : SCALE * LOG2E;

  f32x4 acc[8][4];
#pragma unroll
  for (int m = 0; m < 8; ++m)
#pragma unroll
    for (int n = 0; n < 4; ++n) acc[m][n] = 0.f;

  const u16* sPtr[8];
  int dOff[8];
#pragma unroll
  for (int i = 0; i < 8; ++i) {
    int i2 = i & 3;
    int u = i2 * 512 + t;
    int row = u >> 3, p = u & 7;
    int cu = (p ^ row) & 7;
    const u16* base = (i < 4) ? (A + (size_t)(m0 + row) * Dc)
                              : (W + (size_t)(n0 + row) * Dc);
    sPtr[i] = base + cu * 8;
    dOff[i] = ((i >= 4) ? 32768 : 0) + (i2 >> 1) * 16384 +
              ((i2 & 1) * 512 + (t & 448)) * 16;
  }

  auto STAGE = [&](int d) {
#pragma unroll
    for (int i = 0; i < 8; ++i) {
      gload16(sPtr[i], L + d * 65536 + dOff[i]);
      sPtr[i] += 64;
    }
  };

  STAGE(0);
  asm volatile("s_waitcnt vmcnt(0)" ::: "memory");
  asm volatile("s_barrier" ::: "memory");

  int cur = 0;
  const char* AbBase = L + wm * 16384;
  const char* BbBase = L + 32768 + (wn >> 1) * 16384;
  const int rB0 = (wn & 1) * 64;

#pragma unroll 1
  for (int s = 0; s < 32; ++s) {
    if (s + 1 < 32) {
      STAGE(cur ^ 1);
      asm volatile("s_waitcnt vmcnt(8)" ::: "memory");
    } else {
      asm volatile("s_waitcnt vmcnt(0)" ::: "memory");
    }
    asm volatile("s_barrier" ::: "memory");

    const char* Ab = AbBase + cur * 65536;
    const char* Bb = BbBase + cur * 65536;
#pragma unroll
    for (int mh = 0; mh < 2; ++mh)
#pragma unroll
      for (int ks = 0; ks < 2; ++ks) {
        bf16x8 af[4], bf[4];
#pragma unroll
        for (int m4 = 0; m4 < 4; ++m4) {
          int row = (mh * 4 + m4) * 16 + c;
          af[m4] = *(const bf16x8*)(Ab + row * 128 + (((ks * 4 + g) ^ row) & 7) * 16);
        }
#pragma unroll
        for (int n = 0; n < 4; ++n) {
          int row = rB0 + n * 16 + c;
          bf[n] = *(const bf16x8*)(Bb + row * 128 + (((ks * 4 + g) ^ row) & 7) * 16);
        }
        __builtin_amdgcn_s_setprio(1);
#pragma unroll
        for (int m4 = 0; m4 < 4; ++m4)
#pragma unroll
          for (int n = 0; n < 4; ++n)
            acc[mh * 4 + m4][n] =
                __builtin_amdgcn_mfma_f32_16x16x32_bf16(af[m4], bf[n], acc[mh * 4 + m4][n], 0, 0, 0);
        __builtin_amdgcn_s_setprio(0);
      }

    asm volatile("s_barrier" ::: "memory");
    cur ^= 1;
  }

  u16* outp = z ? kout : qout;
#pragma unroll
  for (int n = 0; n < 4; ++n) {
    int col = n0 + wn * 64 + n * 16 + c;
    float bvv = bias[col];
    int h = col >> 7, d = col & (HDc - 1);
#pragma unroll
    for (int m = 0; m < 8; ++m)
#pragma unroll
      for (int r = 0; r < 4; ++r) {
        int row = m0 + wm * 128 + m * 16 + g * 4 + r;
        int b = row >> 11, si = row & (Sc - 1);
        outp[((size_t)((b * Hc + h) * Sc + si)) * HDc + d] =
            f2bf((acc[m][n][r] + bvv) * scale);
      }
  }
}

// ==== 256Mx128N-tile 8-wave counted-vmcnt GEMM body (shared by V / O) =====
// 256 WGs (16x16) = 1/CU. Waves 2M x 4N, each 128x32. LDS 96KB dbuf
// (48KB = 32KB A + 16KB B per buffer). STAGE = 6 gload16/thread.
#define GEMM256x128_LOOP(Aptr, Wptr)                                          \
  f32x4 acc[8][2];                                                            \
  _Pragma("unroll") for (int m = 0; m < 8; ++m)                               \
      _Pragma("unroll") for (int n = 0; n < 2; ++n) acc[m][n] = 0.f;          \
  const u16* sPtr[6];                                                         \
  int dOff[6];                                                                \
  _Pragma("unroll") for (int i = 0; i < 6; ++i) {                             \
    if (i < 4) {                                                              \
      int u = i * 512 + t, row = u >> 3, p = u & 7;                           \
      int cu = (p ^ row) & 7;                                                 \
      sPtr[i] = Aptr + (size_t)(m0 + row) * Dc + cu * 8;                      \
      dOff[i] = (i * 512 + (t & 448)) * 16;                                   \
    } else {                                                                  \
      int u = (i - 4) * 512 + t, row = u >> 3, p = u & 7;                     \
      int cu = (p ^ row) & 7;                                                 \
      sPtr[i] = Wptr + (size_t)(n0 + row) * Dc + cu * 8;                      \
      dOff[i] = 32768 + ((i - 4) * 512 + (t & 448)) * 16;                     \
    }                                                                         \
  }                                                                           \
  auto STG = [&](int d) {                                                     \
    _Pragma("unroll") for (int i = 0; i < 6; ++i) {                           \
      gload16(sPtr[i], L + d * 49152 + dOff[i]);                              \
      sPtr[i] += 64;                                                          \
    }                                                                         \
  };                                                                          \
  STG(0);                                                                     \
  asm volatile("s_waitcnt vmcnt(0)" ::: "memory");                            \
  asm volatile("s_barrier" ::: "memory");                                     \
  int cur = 0;                                                                \
  _Pragma("unroll 1") for (int s = 0; s < 32; ++s) {                          \
    if (s + 1 < 32) {                                                         \
      STG(cur ^ 1);                                                           \
      asm volatile("s_waitcnt vmcnt(6)" ::: "memory");                        \
    } else {                                                                  \
      asm volatile("s_waitcnt vmcnt(0)" ::: "memory");                        \
    }                                                                         \
    asm volatile("s_barrier" ::: "memory");                                   \
    const char* Ab = L + cur * 49152;                                         \
    const char* Bb = Ab + 32768;                                              \
    _Pragma("unroll") for (int mh = 0; mh < 2; ++mh)                          \
        _Pragma("unroll") for (int ks = 0; ks < 2; ++ks) {                    \
      bf16x8 af[4], bf[2];                                                    \
      _Pragma("unroll") for (int m4 = 0; m4 < 4; ++m4) {                      \
        int row = wm * 128 + (mh * 4 + m4) * 16 + c;                          \
        af[m4] = *(const bf16x8*)(Ab + row * 128 +                            \
                                  (((ks * 4 + g) ^ row) & 7) * 16);           \
      }                                                                       \
      _Pragma("unroll") for (int n = 0; n < 2; ++n) {                         \
        int row = wn * 32 + n * 16 + c;                                       \
        bf[n] = *(const bf16x8*)(Bb + row * 128 +                             \
                                 (((ks * 4 + g) ^ row) & 7) * 16);            \
      }                                                                       \
      __builtin_amdgcn_s_setprio(1);                                          \
      _Pragma("unroll") for (int m4 = 0; m4 < 4; ++m4)                        \
          _Pragma("unroll") for (int n = 0; n < 2; ++n)                       \
              acc[mh * 4 + m4][n] = __builtin_amdgcn_mfma_f32_16x16x32_bf16(  \
                  af[m4], bf[n], acc[mh * 4 + m4][n], 0, 0, 0);               \
      __builtin_amdgcn_s_setprio(0);                                          \
    }                                                                         \
    asm volatile("s_barrier" ::: "memory");                                   \
    cur ^= 1;                                                                 \
  }

// ------- V GEMM: 256x128 tile; epilogue transposes + per-32 k-perm --------
__global__ __launch_bounds__(512, 2) void v_gemm(
    const u16* __restrict__ A, const u16* __restrict__ W,
    const float* __restrict__ bias, u16* __restrict__ vout) {
  __shared__ u16 smem[49152];     // 96 KB
  char* L = (char*)smem;
  const int t = threadIdx.x, w = t >> 6, lane = t & 63, g = lane >> 4, c = lane & 15;
  const int wm = w >> 2, wn = w & 3;
  const int m0 = blockIdx.y * 256, n0 = blockIdx.x * 128;

  GEMM256x128_LOOP(A, W)

  // transpose through LDS: CT[d 128][s 256 + pitch 264]
  u16* CT = smem;
  __syncthreads();
#pragma unroll
  for (int m = 0; m < 8; ++m)
#pragma unroll
    for (int n = 0; n < 2; ++n) {
      int lcol = wn * 32 + n * 16 + c;          // d (local, 0..127)
      float bvv = bias[n0 + lcol];
#pragma unroll
      for (int r = 0; r < 4; ++r) {
        int lrow = wm * 128 + m * 16 + g * 4 + r;   // s (local, 0..255)
        CT[lcol * 264 + lrow] = f2bf(acc[m][n][r] + bvv);
      }
    }
  __syncthreads();
  const int b = m0 >> 11, h = n0 >> 7, s0 = m0 & (Sc - 1);
#pragma unroll
  for (int i = 0; i < 8; ++i) {
    int u = i * 512 + t;                        // 0..4095
    int d = u >> 5, su = u & 31;                // d 0..127, su 0..31
    size_t gbase = ((size_t)((b * Hc + h) * HDc) + d) * Sc + s0;
#pragma unroll
    for (int p2 = 0; p2 < 4; ++p2) {
      int sl = su * 8 + p2 * 2;                 // even local s, 0..255
      u32 val = (u32)CT[d * 264 + sl] | ((u32)CT[d * 264 + sl + 1] << 16);
      int w6 = sl & 63, blk = sl >> 6;
      int slot = ((w6 >> 5) << 5) | (((w6 >> 2) & 3) << 3) |
                 (((w6 >> 4) & 1) << 2) | (w6 & 3);
      *(u32*)&vout[gbase + blk * 64 + slot] = val;
    }
  }
}

// ----- O-projection GEMM: 256x128 tile, fp32 [M,N] epilogue to d_out ------
__global__ __launch_bounds__(512, 2) void gemm_out(
    const u16* __restrict__ A, const u16* __restrict__ W,
    const float* __restrict__ bias, float* __restrict__ outp) {
  __shared__ u16 smem[49152];     // 96 KB
  char* L = (char*)smem;
  const int t = threadIdx.x, w = t >> 6, lane = t & 63, g = lane >> 4, c = lane & 15;
  const int wm = w >> 2, wn = w & 3;
  const int m0 = blockIdx.y * 256, n0 = blockIdx.x * 128;

  GEMM256x128_LOOP(A, W)

#pragma unroll
  for (int n = 0; n < 2; ++n) {
    int col = n0 + wn * 32 + n * 16 + c;
    float bv = bias[col];
#pragma unroll
    for (int m = 0; m < 8; ++m)
#pragma unroll
      for (int r = 0; r < 4; ++r) {
        int row = m0 + wm * 128 + m * 16 + g * 4 + r;
        outp[(size_t)row * Dc + col] = acc[m][n][r] + bv;
      }
  }
}

// ======== attention v9: counted-vmcnt double-buffered pipeline ========
// 512 blocks (XCD-swz, 4 heads/XCD), 256 thr = 4 waves, 32 q/wave (two
// 16-q sets) -> 128 q/block. K+V double-buffered (64KB -> 2 blocks/CU,
// 8 waves/CU). Per tile: mask loads -> STAGE(next) -> vmcnt(16) [drains
// only tile-kt staging] -> raw s_barrier -> compute -> raw s_barrier.
// Swapped QK^T, in-lane P pack (k-permuted V), exp2 softmax.
__global__ __launch_bounds__(256) void attn_mfma(
    const u16* __restrict__ Q, const u16* __restrict__ K,
    const u16* __restrict__ VT, const float* __restrict__ mask,
    u16* __restrict__ outb) {
  __shared__ u16 Ks[2][64 * 128];   // 16KB each
  __shared__ u16 Vt[2][64 * 128];
  const int t = threadIdx.x, w = t >> 6, lane = t & 63, g = lane >> 4, c = lane & 15;
  const int bid = blockIdx.x;
  const int nid = (bid & 7) * 64 + (bid >> 3);   // 512%8==0 bijective
  const int bh = nid >> 4;                       // head (4 heads/XCD)
  const int q0 = (nid & 15) * 128;               // 128 q-rows per block
  const int bq = bh >> 4, h = bh & 15;
  const u16* Qp = Q + ((size_t)bh << 18);
  const u16* Kp = K + ((size_t)bh << 18);
  const u16* VTp = VT + ((size_t)bh << 18);

  const u16* kSrc[4];
  const u16* vSrc[4];
  int kOff[4], vOff[4];
#pragma unroll
  for (int i = 0; i < 4; ++i) {
    int u = i * 256 + t;
    int row = u >> 4, p = u & 15;
    int cu = (p & 8) | ((p ^ row) & 7);
    kSrc[i] = Kp + (size_t)row * HDc + cu * 8;
    kOff[i] = (i * 256 + (t & 192)) * 16;
    int d = u >> 3, pv = u & 7;
    int cv = (pv ^ d) & 7;
    vSrc[i] = VTp + (size_t)d * Sc + cv * 8;
    vOff[i] = (i * 256 + (t & 192)) * 16;
  }

  auto STAGE = [&](int buf) {
#pragma unroll
    for (int i = 0; i < 4; ++i) {
      gload16(kSrc[i], (char*)Ks[buf] + kOff[i]);
      kSrc[i] += 64 * HDc;
    }
#pragma unroll
    for (int i = 0; i < 4; ++i) {
      gload16(vSrc[i], (char*)Vt[buf] + vOff[i]);
      vSrc[i] += 64;
    }
  };

  bf16x8 qf0[4], qf1[4];
  {
    int qr0 = q0 + w * 32 + c;
#pragma unroll
    for (int d0 = 0; d0 < 4; ++d0) {
      qf0[d0] = *(const bf16x8*)(Qp + (size_t)qr0 * HDc + d0 * 32 + g * 8);
      qf1[d0] = *(const bf16x8*)(Qp + (size_t)(qr0 + 16) * HDc + d0 * 32 + g * 8);
    }
  }

  f32x4 po0[8], po1[8];
#pragma unroll
  for (int m = 0; m < 8; ++m) { po0[m] = 0.f; po1[m] = 0.f; }
  float lsum0 = 0.f, lsum1 = 0.f;
  const float* mrow0 = mask + ((size_t)bq * Sc + q0 + w * 32 + c) * Sc;
  const float* mrow1 = mrow0 + (size_t)16 * Sc;

  STAGE(0);
  asm volatile("s_waitcnt vmcnt(0)" ::: "memory");
  asm volatile("s_barrier" ::: "memory");
  int cur = 0;

#pragma unroll 1
  for (int kt = 0; kt < 32; ++kt) {
    const int k0 = kt * 64;
    float4 mk0[4], mk1[4];
#pragma unroll
    for (int n = 0; n < 4; ++n) {
      mk0[n] = *(const float4*)(mrow0 + k0 + n * 16 + g * 4);
      mk1[n] = *(const float4*)(mrow1 + k0 + n * 16 + g * 4);
    }
    if (kt + 1 < 32) {
      STAGE(cur ^ 1);
      asm volatile("s_waitcnt vmcnt(16)" ::: "memory");
    } else {
      asm volatile("s_waitcnt vmcnt(8)" ::: "memory");
    }
    asm volatile("s_barrier" ::: "memory");

    const char* Ksb = (const char*)Ks[cur];
    const char* Vtb = (const char*)Vt[cur];

    f32x4 sfr0[4], sfr1[4];
#pragma unroll
    for (int n = 0; n < 4; ++n) { sfr0[n] = 0.f; sfr1[n] = 0.f; }
    __builtin_amdgcn_s_setprio(1);
#pragma unroll
    for (int ds = 0; ds < 4; ++ds)
#pragma unroll
      for (int n = 0; n < 4; ++n) {
        int row = n * 16 + c;
        int cu = ds * 4 + g;
        int scu = (cu & 8) | ((cu ^ row) & 7);
        bf16x8 kf = *(const bf16x8*)(Ksb + row * 256 + scu * 16);
        sfr0[n] = __builtin_amdgcn_mfma_f32_16x16x32_bf16(kf, qf0[ds], sfr0[n], 0, 0, 0);
        sfr1[n] = __builtin_amdgcn_mfma_f32_16x16x32_bf16(kf, qf1[ds], sfr1[n], 0, 0, 0);
      }
    __builtin_amdgcn_s_setprio(0);

    u32 a01[4], a23[4], b01[4], b23[4];
#pragma unroll
    for (int n = 0; n < 4; ++n) {
      float p0 = __builtin_amdgcn_exp2f(fmaf(mk0[n].x, LOG2E, sfr0[n][0]));
      float p1 = __builtin_amdgcn_exp2f(fmaf(mk0[n].y, LOG2E, sfr0[n][1]));
      float p2 = __builtin_amdgcn_exp2f(fmaf(mk0[n].z, LOG2E, sfr0[n][2]));
      float p3 = __builtin_amdgcn_exp2f(fmaf(mk0[n].w, LOG2E, sfr0[n][3]));
      lsum0 += (p0 + p1) + (p2 + p3);
      a01[n] = (u32)f2bf(p0) | ((u32)f2bf(p1) << 16);
      a23[n] = (u32)f2bf(p2) | ((u32)f2bf(p3) << 16);
      float r0 = __builtin_amdgcn_exp2f(fmaf(mk1[n].x, LOG2E, sfr1[n][0]));
      float r1 = __builtin_amdgcn_exp2f(fmaf(mk1[n].y, LOG2E, sfr1[n][1]));
      float r2 = __builtin_amdgcn_exp2f(fmaf(mk1[n].z, LOG2E, sfr1[n][2]));
      float r3 = __builtin_amdgcn_exp2f(fmaf(mk1[n].w, LOG2E, sfr1[n][3]));
      lsum1 += (r0 + r1) + (r2 + r3);
      b01[n] = (u32)f2bf(r0) | ((u32)f2bf(r1) << 16);
      b23[n] = (u32)f2bf(r2) | ((u32)f2bf(r3) << 16);
    }

    __builtin_amdgcn_s_setprio(1);
#pragma unroll
    for (int s2 = 0; s2 < 2; ++s2) {
      uint4 pw0, pw1;
      pw0.x = a01[s2 * 2]; pw0.y = a23[s2 * 2];
      pw0.z = a01[s2 * 2 + 1]; pw0.w = a23[s2 * 2 + 1];
      pw1.x = b01[s2 * 2]; pw1.y = b23[s2 * 2];
      pw1.z = b01[s2 * 2 + 1]; pw1.w = b23[s2 * 2 + 1];
      bf16x8 pf0 = __builtin_bit_cast(bf16x8, pw0);
      bf16x8 pf1 = __builtin_bit_cast(bf16x8, pw1);
#pragma unroll
      for (int m = 0; m < 8; ++m) {
        int d = m * 16 + c;
        int scuv = ((s2 * 4 + g) ^ (d & 7)) & 7;
        bf16x8 vf = *(const bf16x8*)(Vtb + d * 128 + scuv * 16);
        po0[m] = __builtin_amdgcn_mfma_f32_16x16x32_bf16(vf, pf0, po0[m], 0, 0, 0);
        po1[m] = __builtin_amdgcn_mfma_f32_16x16x32_bf16(vf, pf1, po1[m], 0, 0, 0);
      }
    }
    __builtin_amdgcn_s_setprio(0);
    asm volatile("s_barrier" ::: "memory");
    cur ^= 1;
  }

  lsum0 += __shfl_xor(lsum0, 16, 64);
  lsum0 += __shfl_xor(lsum0, 32, 64);
  lsum1 += __shfl_xor(lsum1, 16, 64);
  lsum1 += __shfl_xor(lsum1, 32, 64);
  const float rl0 = 1.0f / lsum0;
  const float rl1 = 1.0f / lsum1;
  const int qg0 = q0 + w * 32 + c;
  u16* ob0 = outb + ((size_t)(bq * Sc + qg0)) * Dc + h * HDc;
  u16* ob1 = ob0 + (size_t)16 * Dc;
#pragma unroll
  for (int m = 0; m < 8; ++m) {
    ushort4 o4;
    o4.x = f2bf(po0[m][0] * rl0);
    o4.y = f2bf(po0[m][1] * rl0);
    o4.z = f2bf(po0[m][2] * rl0);
    o4.w = f2bf(po0[m][3] * rl0);
    *(ushort4*)(ob0 + m * 16 + g * 4) = o4;
    ushort4 o5;
    o5.x = f2bf(po1[m][0] * rl1);
    o5.y = f2bf(po1[m][1] * rl1);
    o5.z = f2bf(po1[m][2] * rl1);
    o5.w = f2bf(po1[m][3] * rl1);
    *(ushort4*)(ob1 + m * 16 + g * 4) = o5;
  }
}

// ---------------- launch ----------------
extern "C" void kernel_launch(void* const* d_in, const int* in_sizes, int n_in,
                              void* d_out, int out_size, void* d_ws,
                              size_t ws_size, hipStream_t stream) {
  const float* hs   = (const float*)d_in[0];
  const float* mask = (const float*)d_in[1];
  const float* Wq   = (const float*)d_in[2];
  const float* bqp  = (const float*)d_in[3];
  const float* Wk   = (const float*)d_in[4];
  const float* bkp  = (const float*)d_in[5];
  const float* Wv   = (const float*)d_in[6];
  const float* bvp  = (const float*)d_in[7];
  const float* Wo   = (const float*)d_in[8];
  const float* bop  = (const float*)d_in[9];

  u16* Xb  = (u16*)d_ws;                 // [4096][2048] bf16
  u16* Wqb = Xb + (size_t)Mc * Dc;
  u16* Wkb = Wqb + (size_t)Dc * Dc;
  u16* Wvb = Wkb + (size_t)Dc * Dc;
  u16* Wob = Wvb + (size_t)Dc * Dc;
  u16* qb  = Wob + (size_t)Dc * Dc;      // [B,H,S,HD] bf16 (scaled SCALE*log2e)
  u16* kb  = qb + (size_t)Mc * Dc;       // [B,H,S,HD] bf16
  u16* vtb = kb + (size_t)Mc * Dc;       // [B,H,HD,S] bf16, k-permuted /32
  u16* ab  = vtb + (size_t)Mc * Dc;      // [B,S,D] bf16

  const int nh4 = Mc * Dc / 4;
  const int nw4 = Dc * Dc / 4;
  cvt5<<<dim3((nh4 + 4 * nw4) / 256), dim3(256), 0, stream>>>(
      hs, Xb, nh4, Wq, Wqb, nw4, Wk, Wkb, nw4, Wv, Wvb, nw4, Wo, Wob, nw4);

  qk_gemm8<<<dim3(Dc / 256, Mc / 256, 2), dim3(512), 0, stream>>>(
      Xb, Wqb, Wkb, bqp, bkp, qb, kb);
  v_gemm<<<dim3(Dc / 128, Mc / 256), dim3(512), 0, stream>>>(
      Xb, Wvb, bvp, vtb);
  attn_mfma<<<dim3(512), dim3(256), 0, stream>>>(qb, kb, vtb, mask, ab);
  gemm_out<<<dim3(Dc / 128, Mc / 256), dim3(512), 0, stream>>>(
      ab, Wob, bop, (float*)d_out);
}